// Round 17
// baseline (681.910 us; speedup 1.0000x reference)
//
#include <hip/hip_runtime.h>

typedef unsigned short u16;
typedef unsigned int u32;
typedef long long i64;
typedef __attribute__((ext_vector_type(4))) float f32x4;
typedef __attribute__((ext_vector_type(8))) __bf16 bf16x8;

#define DEVI static __device__ __forceinline__

constexpr int kB = 4, kS = 2048, kD = 512, kH = 8;
constexpr int kND = kD * kH;     // 4096
constexpr int kBS = kB * kS;     // 8192
constexpr int kNQK = 2 * kND;    // 8192
constexpr int kNQKV = 3 * kND;   // 12288
constexpr float kScale = 0.044194173824159216f;  // 512^-0.5

DEVI u16 f2bf(float f) {
  u32 u = __builtin_bit_cast(u32, f);
  return (u16)((u + 0x7fffu + ((u >> 16) & 1u)) >> 16);
}
DEVI float bf2f(u16 h) { return __builtin_bit_cast(float, (u32)h << 16); }

DEVI f32x4 mfma16(bf16x8 a, bf16x8 b, f32x4 c) {
  return __builtin_amdgcn_mfma_f32_16x16x32_bf16(a, b, c, 0, 0, 0);
}

// global -> LDS direct DMA, 16B per lane (wave-uniform LDS base + lane*16)
DEVI void gld16(const u16* g, u16* l) {
  __builtin_amdgcn_global_load_lds(
      (const __attribute__((address_space(1))) void*)g,
      (__attribute__((address_space(3))) void*)l, 16, 0, 0);
}

__global__ void k_zero(float* __restrict__ p, int n) {
  int i = blockIdx.x * 256 + threadIdx.x;
  if (i < n) p[i] = 0.0f;
}

// concat q_b|k_b|v_b -> [12288]
__global__ void k_cat3(const float* __restrict__ a, const float* __restrict__ b,
                       const float* __restrict__ c, float* __restrict__ o) {
  int i = blockIdx.x * 256 + threadIdx.x;
  if (i < kND) o[i] = a[i];
  else if (i < 2 * kND) o[i] = b[i - kND];
  else if (i < 3 * kND) o[i] = c[i - 2 * kND];
}

// sum 4 split-K partial planes + bias -> fp32 out; NP = float4s per plane
__global__ __launch_bounds__(256) void k_red4(const float* __restrict__ p,
                                              const float* __restrict__ bias,
                                              float* __restrict__ out, int NP) {
  const int i = blockIdx.x * 256 + threadIdx.x;  // float4 index
  const float4* pv = reinterpret_cast<const float4*>(p);
  const float4 a = pv[i], b = pv[i + NP], c = pv[i + 2 * NP],
               d = pv[i + 3 * NP];
  const float4 bv = reinterpret_cast<const float4*>(bias)[i & 127];
  float4 r;
  r.x = a.x + b.x + c.x + d.x + bv.x;
  r.y = a.y + b.y + c.y + d.y + bv.y;
  r.z = a.z + b.z + c.z + d.z + bv.z;
  r.w = a.w + b.w + c.w + d.w + bv.w;
  reinterpret_cast<float4*>(out)[i] = r;
}

// ---------------- LayerNorm: fp32 [8192,512] -> bf16 xn ----------------
__global__ __launch_bounds__(256) void k_ln(const float* __restrict__ x,
                                            const float* __restrict__ lw,
                                            const float* __restrict__ lb,
                                            u16* __restrict__ xn) {
  const int lane = threadIdx.x & 63;
  const int row = (blockIdx.x << 2) + (threadIdx.x >> 6);
  const float4* xp = reinterpret_cast<const float4*>(x + (size_t)row * kD);
  float4 a = xp[lane * 2], b = xp[lane * 2 + 1];
  float s = a.x + a.y + a.z + a.w + b.x + b.y + b.z + b.w;
  float ss = a.x * a.x + a.y * a.y + a.z * a.z + a.w * a.w +
             b.x * b.x + b.y * b.y + b.z * b.z + b.w * b.w;
#pragma unroll
  for (int m = 1; m < 64; m <<= 1) {
    s += __shfl_xor(s, m, 64);
    ss += __shfl_xor(ss, m, 64);
  }
  const float mean = s * (1.0f / kD);
  const float var = ss * (1.0f / kD) - mean * mean;
  const float rstd = rsqrtf(fmaxf(var, 0.0f) + 1e-5f);
  const float4* wp = reinterpret_cast<const float4*>(lw);
  const float4* bp = reinterpret_cast<const float4*>(lb);
  float4 w0 = wp[lane * 2], w1 = wp[lane * 2 + 1];
  float4 b0 = bp[lane * 2], b1 = bp[lane * 2 + 1];
  float o0 = (a.x - mean) * rstd * w0.x + b0.x;
  float o1 = (a.y - mean) * rstd * w0.y + b0.y;
  float o2 = (a.z - mean) * rstd * w0.z + b0.z;
  float o3 = (a.w - mean) * rstd * w0.w + b0.w;
  float o4 = (b.x - mean) * rstd * w1.x + b1.x;
  float o5 = (b.y - mean) * rstd * w1.y + b1.y;
  float o6 = (b.z - mean) * rstd * w1.z + b1.z;
  float o7 = (b.w - mean) * rstd * w1.w + b1.w;
  uint4 st = make_uint4((u32)f2bf(o0) | ((u32)f2bf(o1) << 16),
                        (u32)f2bf(o2) | ((u32)f2bf(o3) << 16),
                        (u32)f2bf(o4) | ((u32)f2bf(o5) << 16),
                        (u32)f2bf(o6) | ((u32)f2bf(o7) << 16));
  *reinterpret_cast<uint4*>(xn + (size_t)row * kD + lane * 8) = st;
}

// ------------- weight transpose: fp32 [R,C] -> bf16 [C,R] -------------
__global__ void k_wt(const float* __restrict__ in, u16* __restrict__ out,
                     int R, int C) {
  __shared__ float t[32][33];
  const int tx = threadIdx.x, ty = threadIdx.y;
  const int c0 = blockIdx.x << 5, r0 = blockIdx.y << 5;
#pragma unroll
  for (int i = 0; i < 4; i++)
    t[ty + 8 * i][tx] = in[(size_t)(r0 + ty + 8 * i) * C + c0 + tx];
  __syncthreads();
#pragma unroll
  for (int i = 0; i < 4; i++)
    out[(size_t)(c0 + ty + 8 * i) * R + r0 + tx] = f2bf(t[tx][ty + 8 * i]);
}

// fused transpose of q_w/k_w/v_w (each fp32 [512,4096] -> bf16 [4096,512])
// into contiguous qkvT slices; z selects the weight.
__global__ void k_wt3(const float* __restrict__ qa, const float* __restrict__ kb,
                      const float* __restrict__ vc, u16* __restrict__ out) {
  __shared__ float t[32][33];
  const int z = blockIdx.z;
  const float* in = (z == 0) ? qa : (z == 1) ? kb : vc;
  u16* o = out + (size_t)z * kND * kD;
  const int tx = threadIdx.x, ty = threadIdx.y;
  const int c0 = blockIdx.x << 5, r0 = blockIdx.y << 5;
#pragma unroll
  for (int i = 0; i < 4; i++)
    t[ty + 8 * i][tx] = in[(size_t)(r0 + ty + 8 * i) * kND + c0 + tx];
  __syncthreads();
#pragma unroll
  for (int i = 0; i < 4; i++)
    o[(size_t)(c0 + ty + 8 * i) * kD + r0 + tx] = f2bf(t[tx][ty + 8 * i]);
}

// ------- V transpose: bf16 V[2048, d-slice] -> VT[z][512][2048] -------
// (used only by fallback plans)
__global__ void k_vt(const u16* __restrict__ V, u16* __restrict__ VT, int ldv,
                     i64 sVz, i64 sVzH, i64 sTz) {
  const int z = blockIdx.z;
  V += (size_t)((i64)z * sVz + (i64)(z >> 3) * sVzH);
  VT += (size_t)((i64)z * sTz);
  __shared__ u16 t[32][33];
  const int tx = threadIdx.x, ty = threadIdx.y;
  const int s0 = blockIdx.x << 5, d0 = blockIdx.y << 5;
#pragma unroll
  for (int i = 0; i < 4; i++)
    t[ty + 8 * i][tx] = V[(size_t)(s0 + ty + 8 * i) * ldv + d0 + tx];
  __syncthreads();
#pragma unroll
  for (int i = 0; i < 4; i++)
    VT[(size_t)(d0 + ty + 8 * i) * kS + s0 + tx] = t[tx][ty + 8 * i];
}

// LDS-transposed C-store index (128-row staging tiles): elem (row,col) at
// row*128 + ((col>>3) ^ (((row>>2)&3)<<1))*8 + (col&7).
DEVI int tidx(int row, int col) {
  return row * 128 + ((((col >> 3) ^ (((row >> 2) & 3) << 1)) << 3) |
                      (col & 7));
}

// ---------------- GEMM body: C[M,N] = A[M,K] * Bt[N,K]^T (+epilogue) -------
// DEPTH=2: proven double-buffer 2-barrier schedule (occupancy-rich kernels).
// DEPTH=3: triple-buffer + counted vmcnt(NLD) pipeline (reg-capped kernels).
// BM=256 doubles wave-tile FLOP per LDS byte (128x64 wave tile) -- with
// DEPTH=3 the counted-vmcnt pipeline covers latency within a block, so the
// 2-blk/CU occupancy cost is tolerable (proven on pv128; now applied to qkt).
// R15 lesson: atomic split-K accumulate REGRESSED; partial planes + k_red4
// (EPI 6) is measured best.
// T1: XCD-chunked bijective block remap (m204). Source+read chunk swizzle.
// EPI 0: bf16 out + bias (LDS-staged coalesced store)        (proj)
// EPI 1: f32  out + bias                                     (O-proj fallback)
// EPI 4: f32  out += acc                                     (O-proj accum)
// EPI 2: bf16 out = exp(acc*scale), atomic row-sums -> lrow  (QK^T)
// EPI 3: bf16 out = acc / lrow[row]                          (P@V)
// EPI 6: f32 partial out (split-K plane per z)               (O-proj)
// EPI 7: fused QKV proj: n0 < 8192 -> EPI0 into Cb; else V into lbase (VT)
template <int EPI, int BN, int BM = 128, int DEPTH = 2>
DEVI void gemm_body(const u16* __restrict__ A, int lda, i64 sAz, i64 sAzH,
                    const u16* __restrict__ Bt, int ldb, i64 sBz, i64 sBzH,
                    void* __restrict__ Cb, int ldc, i64 sCz, i64 sCzH, int K,
                    const float* __restrict__ bias, float* __restrict__ lbase,
                    i64 sLz) {
  constexpr int NF = BN / 32;    // B-frags per wave
  constexpr int MF = BM / 32;    // A-frags per wave
  constexpr int BHALF = BN / 2;  // cols per wave-col
  constexpr int WM = BM / 2;     // rows per wave-row
  constexpr int ABUF = BM * 32, BBUF = BN * 32;  // elems per LDS buffer
  constexpr int NCA = BM / 64, NCB = BN / 64;    // gld16 chunks per wave
  constexpr int NLD = NCA + NCB;                 // per-wave loads per stage
  constexpr int H = BM / 128;    // epilogue flush halves

  // ---- T1 bijective XCD remap (correctness-neutral relabeling) ----
  const u32 gxd = gridDim.x, gyd = gridDim.y;
  const u32 total = gxd * gyd * gridDim.z;
  u32 fid = (blockIdx.z * gyd + blockIdx.y) * gxd + blockIdx.x;
  {
    const u32 q = total >> 3, r = total & 7;
    const u32 xcd = fid & 7, i = fid >> 3;
    fid = (xcd < r ? xcd * (q + 1) : r * (q + 1) + (xcd - r) * q) + i;
  }
  const int bx = fid % gxd;
  const int by = (fid / gxd) % gyd;
  const int z = fid / (gxd * gyd);

  A += (size_t)((i64)z * sAz + (i64)(z >> 3) * sAzH);
  Bt += (size_t)((i64)z * sBz + (i64)(z >> 3) * sBzH);
  const i64 czoff = (i64)z * sCz + (i64)(z >> 3) * sCzH;
  float* lrow = lbase + (size_t)z * sLz;

  __shared__ __align__(16) u16 smem[DEPTH * (ABUF + BBUF)];
  u16* Asb = smem;
  u16* Bsb = smem + DEPTH * ABUF;

  const int tid = threadIdx.x;
  const int lane = tid & 63, wid = tid >> 6;
  const int g = lane >> 4, lr = lane & 15;
  const int wr = wid >> 1, wc = wid & 1;
  const int m0 = bx * BM, n0 = by * BN;

  // staging: wave w covers A rows [w*BM/4, +BM/4) in NCA 16-row chunks;
  // B rows likewise. Chunk-XOR swizzle on the global source (row&3 ==
  // (lane>>2)&3 for all staged rows since chunk offsets are multiples of 16).
  const int scol = (((lane & 3) ^ ((lane >> 2) & 3)) << 3);
  const int l4 = lane >> 2;
  const u16* agp[NCA];
#pragma unroll
  for (int c = 0; c < NCA; c++)
    agp[c] = A + (size_t)(m0 + wid * (BM / 4) + 16 * c + l4) * lda + scol;
  const u16* bgp[NCB];
#pragma unroll
  for (int c = 0; c < NCB; c++)
    bgp[c] = Bt + (size_t)(n0 + wid * (BN / 4) + 16 * c + l4) * ldb + scol;

  f32x4 acc[MF][NF] = {};

  auto stage = [&](int ks, int buf) {
    const int ko = ks << 5;
    u16* ab = Asb + buf * ABUF + wid * (BM / 4) * 32;
#pragma unroll
    for (int c = 0; c < NCA; c++) gld16(agp[c] + ko, ab + c * 512);
    u16* bb = Bsb + buf * BBUF + wid * (BN / 4) * 32;
#pragma unroll
    for (int c = 0; c < NCB; c++) gld16(bgp[c] + ko, bb + c * 512);
  };

  // read-side swizzle: fragment rows R have R&3 == lr&3
  const int gx8 = ((g ^ (lr & 3)) << 3);

  const int nsteps = K >> 5;
  if constexpr (DEPTH == 2) {
    stage(0, 0);
    for (int ks = 0; ks < nsteps; ++ks) {
      const int cur = ks & 1;
      __syncthreads();  // drains vmcnt -> tile `cur` ready; prior reads done
      if (ks + 1 < nsteps) stage(ks + 1, cur ^ 1);
      bf16x8 af[MF], bfr[NF];
#pragma unroll
      for (int m = 0; m < MF; m++)
        af[m] = *reinterpret_cast<const bf16x8*>(
            &Asb[cur * ABUF + (wr * WM + m * 16 + lr) * 32 + gx8]);
#pragma unroll
      for (int n = 0; n < NF; n++)
        bfr[n] = *reinterpret_cast<const bf16x8*>(
            &Bsb[cur * BBUF + (wc * BHALF + n * 16 + lr) * 32 + gx8]);
#pragma unroll
      for (int m = 0; m < MF; m++)
#pragma unroll
        for (int n = 0; n < NF; n++)
          acc[m][n] = mfma16(af[m], bfr[n], acc[m][n]);
    }
  } else {
    stage(0, 0);
    stage(1, 1);
    for (int ks = 0; ks < nsteps; ++ks) {
      const int cur = ks % 3;
      // tile ks must be landed; newest stage (tile ks+1) may stay in flight
      if (ks + 1 < nsteps) {
        if constexpr (NLD == 3) asm volatile("s_waitcnt vmcnt(3)" ::: "memory");
        else if constexpr (NLD == 4) asm volatile("s_waitcnt vmcnt(4)" ::: "memory");
        else if constexpr (NLD == 6) asm volatile("s_waitcnt vmcnt(6)" ::: "memory");
        else asm volatile("s_waitcnt vmcnt(0)" ::: "memory");
      } else {
        asm volatile("s_waitcnt vmcnt(0)" ::: "memory");
      }
      __builtin_amdgcn_s_barrier();
      if (ks + 2 < nsteps) stage(ks + 2, (ks + 2) % 3);
      bf16x8 af[MF], bfr[NF];
#pragma unroll
      for (int m = 0; m < MF; m++)
        af[m] = *reinterpret_cast<const bf16x8*>(
            &Asb[cur * ABUF + (wr * WM + m * 16 + lr) * 32 + gx8]);
#pragma unroll
      for (int n = 0; n < NF; n++)
        bfr[n] = *reinterpret_cast<const bf16x8*>(
            &Bsb[cur * BBUF + (wc * BHALF + n * 16 + lr) * 32 + gx8]);
      asm volatile("s_waitcnt lgkmcnt(0)" ::: "memory");
      __builtin_amdgcn_sched_barrier(0);
      __builtin_amdgcn_s_setprio(1);
#pragma unroll
      for (int m = 0; m < MF; m++)
#pragma unroll
        for (int n = 0; n < NF; n++)
          acc[m][n] = mfma16(af[m], bfr[n], acc[m][n]);
      __builtin_amdgcn_s_setprio(0);
    }
  }

  const int crow0 = m0 + wr * WM;
  const int ccol0 = n0 + wc * BHALF;

  // coalesced bf16 readout of 128-row staging tile -> global (BN=128 only)
  auto flushRows = [&](u16* C16, int ld, int rbase) {
#pragma unroll
    for (int it = 0; it < 8; ++it) {
      const int r = it * 16 + (tid >> 4);
      const int b = tid & 15;
      const int sb = b ^ (((r >> 2) & 3) << 1);
      *reinterpret_cast<uint4*>(C16 + (size_t)(m0 + rbase + r) * ld + n0 +
                                b * 8) =
          *reinterpret_cast<const uint4*>(&smem[r * 128 + sb * 8]);
    }
  };

  if constexpr (EPI == 0 || EPI == 7) {
    const bool qkpart = (EPI == 0) || (n0 < kNQK);
    if (qkpart) {
      __syncthreads();  // K-loop LDS dead; reuse as staging tile
#pragma unroll
      for (int n = 0; n < NF; n++) {
        const int cl = wc * BHALF + n * 16 + lr;
        const float bv = bias[n0 + cl];
#pragma unroll
        for (int m = 0; m < MF; m++)
#pragma unroll
          for (int j = 0; j < 4; j++) {
            const int rl = wr * WM + m * 16 + (g << 2) + j;
            smem[tidx(rl, cl)] = f2bf(acc[m][n][j] + bv);
          }
      }
      u16* C16 = (u16*)Cb + (size_t)czoff;
      __syncthreads();
      flushRows(C16, ldc, 0);
    } else {
      // V branch of fused proj: transposed write into VT[zb][d][s]
      u16* T = smem;
      __syncthreads();
      const int ndl = n0 - kNQK;  // d-col base within [0,4096)
#pragma unroll
      for (int n = 0; n < NF; n++) {
        const int cl = wc * BHALF + n * 16 + lr;  // d_local
        const float bv = bias[n0 + cl];
#pragma unroll
        for (int m = 0; m < MF; m++) {
          const int rlb = wr * WM + m * 16 + (g << 2);  // s_local base
#pragma unroll
          for (int j = 0; j < 4; j++) {
            const int rl = rlb + j;
            T[cl * 128 + ((((rl >> 3) ^ (cl & 7)) << 3) | (rl & 7))] =
                f2bf(acc[m][n][j] + bv);
          }
        }
      }
      __syncthreads();
      const int zb = ((m0 >> 11) << 3) + (ndl >> 9);  // b'*8 + h
      u16* VT = (u16*)lbase + (size_t)zb * kD * kS +
                (size_t)(ndl & 511) * kS + (m0 & 2047);
#pragma unroll
      for (int p = 0; p < 8; p++) {
        const int dl = p * 16 + (tid >> 4);
        const int r8 = tid & 15;
        *reinterpret_cast<uint4*>(VT + (size_t)dl * kS + (r8 << 3)) =
            *reinterpret_cast<const uint4*>(
                &T[dl * 128 + ((r8 ^ (dl & 7)) << 3)]);
      }
    }
  } else if constexpr (EPI == 1 || EPI == 4 || EPI == 6) {
    float* C32 = (float*)Cb + (size_t)czoff;
#pragma unroll
    for (int n = 0; n < NF; n++) {
      const int col = ccol0 + n * 16 + lr;
      const float bv = (EPI == 1) ? bias[col] : 0.0f;
#pragma unroll
      for (int m = 0; m < MF; m++)
#pragma unroll
        for (int j = 0; j < 4; j++) {
          const int row = crow0 + m * 16 + (g << 2) + j;
          float v = acc[m][n][j] + bv;
          if constexpr (EPI == 4) v += C32[(size_t)row * ldc + col];
          C32[(size_t)row * ldc + col] = v;
        }
    }
  } else if constexpr (EPI == 2) {
    u16* C16 = (u16*)Cb + (size_t)czoff;
#pragma unroll
    for (int h = 0; h < H; ++h) {
      __syncthreads();  // K-loop reads / previous flush done
      if (H == 1 || wr == h) {
#pragma unroll
        for (int m = 0; m < MF; m++) {
          float rsum[4] = {0.f, 0.f, 0.f, 0.f};
#pragma unroll
          for (int n = 0; n < NF; n++) {
            const int cl = wc * BHALF + n * 16 + lr;
#pragma unroll
            for (int j = 0; j < 4; j++) {
              const int rl = wr * WM - h * 128 + m * 16 + (g << 2) + j;
              const float p = __expf(acc[m][n][j] * kScale);
              const u16 pb = f2bf(p);
              smem[tidx(rl, cl)] = pb;
              rsum[j] += bf2f(pb);  // keep l consistent with stored bf16 P
            }
          }
#pragma unroll
          for (int j = 0; j < 4; j++) {
            float r = rsum[j];
            r += __shfl_xor(r, 1, 64);
            r += __shfl_xor(r, 2, 64);
            r += __shfl_xor(r, 4, 64);
            r += __shfl_xor(r, 8, 64);
            if (lr == 0) atomicAdd(&lrow[crow0 + m * 16 + (g << 2) + j], r);
          }
        }
      }
      __syncthreads();
      flushRows(C16, ldc, h * 128);
    }
  } else if constexpr (EPI == 3) {
    if constexpr (BN == 128) {
      u16* C16 = (u16*)Cb + (size_t)czoff;
#pragma unroll
      for (int h = 0; h < H; ++h) {
        __syncthreads();
        if (H == 1 || wr == h) {
#pragma unroll
          for (int m = 0; m < MF; m++)
#pragma unroll
            for (int j = 0; j < 4; j++) {
              const int rl = wr * WM - h * 128 + m * 16 + (g << 2) + j;
              const float inv = 1.0f / lrow[crow0 + m * 16 + (g << 2) + j];
#pragma unroll
              for (int n = 0; n < NF; n++) {
                const int cl = wc * BHALF + n * 16 + lr;
                smem[tidx(rl, cl)] = f2bf(acc[m][n][j] * inv);
              }
            }
        }
        __syncthreads();
        flushRows(C16, ldc, h * 128);
      }
    } else {
      u16* C16 = (u16*)Cb + (size_t)czoff;
#pragma unroll
      for (int m = 0; m < MF; m++)
#pragma unroll
        for (int j = 0; j < 4; j++) {
          const int row = crow0 + m * 16 + (g << 2) + j;
          const float inv = 1.0f / lrow[row];
#pragma unroll
          for (int n = 0; n < NF; n++) {
            const int col = ccol0 + n * 16 + lr;
            C16[(size_t)row * ldc + col] = f2bf(acc[m][n][j] * inv);
          }
        }
    }
  }
}

#define GEMM_ARGS                                                             \
  const u16 *A, int lda, i64 sAz, i64 sAzH, const u16 *Bt, int ldb, i64 sBz,  \
      i64 sBzH, void *Cb, int ldc, i64 sCz, i64 sCzH, int K,                  \
      const float *bias, float *lbase, i64 sLz
#define GEMM_PASS A, lda, sAz, sAzH, Bt, ldb, sBz, sBzH, Cb, ldc, sCz, sCzH, \
      K, bias, lbase, sLz

__global__ __launch_bounds__(256) void k_qkproj(GEMM_ARGS) {
  gemm_body<0, 128, 128, 2>(GEMM_PASS);
}
__global__ __launch_bounds__(256) void k_qkvproj(GEMM_ARGS) {
  gemm_body<7, 128, 128, 2>(GEMM_PASS);
}
// QK^T: BM=256 wave tile 128x64 (2x FLOP/LDS-byte) + DEPTH=3 counted-vmcnt
// pipeline (the combo that made pv128 fastest; R11's BM=256 regression was
// with the old vmcnt(0)-drain schedule)
__global__ __launch_bounds__(256, 2) void k_qkt(GEMM_ARGS) {
  gemm_body<2, 128, 256, 3>(GEMM_PASS);
}
__global__ __launch_bounds__(256) void k_pv(GEMM_ARGS) {
  gemm_body<3, 64, 128, 2>(GEMM_PASS);
}
// PV: BM=256 (2 blk/CU reg-capped) + DEPTH=3 pipeline
__global__ __launch_bounds__(256, 2) void k_pv128(GEMM_ARGS) {
  gemm_body<3, 128, 256, 3>(GEMM_PASS);
}
// O-proj split-K: f32 partial planes (measured best; atomics regressed)
__global__ __launch_bounds__(256) void k_osplit(GEMM_ARGS) {
  gemm_body<6, 64, 128, 2>(GEMM_PASS);
}
__global__ __launch_bounds__(256) void k_oproj(GEMM_ARGS) {
  gemm_body<1, 128, 128, 2>(GEMM_PASS);
}
__global__ __launch_bounds__(256) void k_oacc(GEMM_ARGS) {
  gemm_body<4, 128, 128, 2>(GEMM_PASS);
}

extern "C" void kernel_launch(void* const* d_in, const int* in_sizes, int n_in,
                              void* d_out, int out_size, void* d_ws,
                              size_t ws_size, hipStream_t stream) {
  const float* x = (const float*)d_in[0];
  const float* ln_w = (const float*)d_in[1];
  const float* ln_b = (const float*)d_in[2];
  const float* q_w = (const float*)d_in[3];
  const float* q_b = (const float*)d_in[4];
  const float* k_w = (const float*)d_in[5];
  const float* k_b = (const float*)d_in[6];
  const float* v_w = (const float*)d_in[7];
  const float* v_b = (const float*)d_in[8];
  const float* o_w = (const float*)d_in[9];
  const float* o_b = (const float*)d_in[10];
  float* out = (float*)d_out;

  // ---- workspace plan, adaptive to ws_size ----
  constexpr size_t SZ_XN = (size_t)kBS * kD * 2;        // 8 MB
  constexpr size_t SZ_QKVT = (size_t)kNQKV * kD * 2;    // 12 MB
  constexpr size_t SZ_OWT = (size_t)kND * kD * 2;       // 4 MB
  constexpr size_t SZ_CB = (size_t)kNQKV * 4;           // 48 KB
  constexpr size_t SZ_LB = (size_t)32 * kS * 4;         // 256 KB
  // per-batch fused-tier pieces:
  constexpr size_t SZ_QK1 = (size_t)kS * kNQK * 2;      // 32 MB (AO aliases)
  constexpr size_t SZ_VT1 = (size_t)8 * kD * kS * 2;    // 16 MB
  constexpr size_t SZ_S1 = (size_t)8 * kS * kS * 2;     // 64 MB
  constexpr size_t SZ_TIER = SZ_QK1 + SZ_VT1 + SZ_S1;   // 112 MB per batch
  // fallback pieces:
  constexpr size_t SZ_AO = (size_t)kBS * kND * 2;       // 64 MB
  constexpr size_t SZ_S = (size_t)kS * kS * 2;          // 8 MB per z
  constexpr size_t SZ_H = (size_t)kBS * kD * 2;         // 8 MB per head
  constexpr size_t SZ_BH = (size_t)kS * kD * 2;         // 2 MB per (b,h)
  const size_t common = SZ_XN + SZ_QKVT + SZ_OWT + SZ_CB + SZ_LB;

  char* p = (char*)d_ws;
  auto alloc = [&](size_t bytes) {
    char* r = p;
    p += (bytes + 255) & ~(size_t)255;
    return r;
  };
  auto fits = [&](size_t extra) { return common + extra + 8192 <= ws_size; };

  int nb = 0, plan = -1, zc = 0;
  if (fits(4 * SZ_TIER)) nb = 4;
  else if (fits(2 * SZ_TIER)) nb = 2;
  else if (fits(1 * SZ_TIER)) nb = 1;
  else if (fits(4 * SZ_H + SZ_AO + 4 * SZ_S)) { plan = 1; zc = 4; }
  else if (fits(4 * SZ_H + SZ_AO + 1 * SZ_S)) { plan = 1; zc = 1; }
  else if (fits(5 * SZ_H + 4 * SZ_S)) { plan = 2; zc = 4; }
  else if (fits(5 * SZ_H + 1 * SZ_S)) { plan = 2; zc = 1; }
  else { plan = 3; zc = 1; }

  u16* xn = (u16*)alloc(SZ_XN);
  u16* qkvT = (u16*)alloc(SZ_QKVT);  // q rows [0,4096), k [4096,8192), v [8192,12288)
  u16* owT = (u16*)alloc(SZ_OWT);
  float* cbias = (float*)alloc(SZ_CB);
  float* lbuf = (float*)alloc(SZ_LB);

  u16* kwT = qkvT + (size_t)kND * kD;
  u16* vwT = qkvT + (size_t)2 * kND * kD;

  // ---- common pre-work ----
  k_zero<<<dim3(256), 256, 0, stream>>>(lbuf, 32 * kS);
  k_ln<<<dim3(kBS / 4), 256, 0, stream>>>(x, ln_w, ln_b, xn);
  dim3 tb(32, 8);
  k_wt3<<<dim3(kND / 32, kD / 32, 3), tb, 0, stream>>>(q_w, k_w, v_w, qkvT);
  k_wt<<<dim3(kD / 32, kND / 32), tb, 0, stream>>>(o_w, owT, kND, kD);

  const i64 sS = (i64)kS * kS;  // S tile stride (elems)

  if (nb > 0) {
    // ---- fused batch-group plan ----
    u16* QKg = (u16*)alloc((size_t)nb * SZ_QK1);
    u16* VTg = (u16*)alloc((size_t)nb * SZ_VT1);
    u16* Sb = (u16*)alloc((size_t)nb * SZ_S1);
    u16* AOg = QKg;           // [nb*2048, 4096] alias; QK dead after qkt
    float* Pb = (float*)Sb;   // split-K partials alias S (dead after pv)

    k_cat3<<<dim3(kNQKV / 256), 256, 0, stream>>>(q_b, k_b, v_b, cbias);

    const i64 sHiA = (i64)kS * kNQK - 8 * kD;   // QK z-jump at batch boundary
    const i64 sHiAO = (i64)kS * kND - 8 * kD;   // AO z-jump at batch boundary
    const int zc8 = nb * 8;

    for (int g = 0; g < kB; g += nb) {
      const u16* xb = xn + (size_t)g * kS * kD;
      // fused QKV projection: [nb*2048,512] x [12288,512]^T
      // cols <8192 -> QKg (bf16+bias); cols >=8192 -> VTg transposed
      k_qkvproj<<<dim3(nb * kS / 128, kNQKV / 128), 256, 0, stream>>>(
          xb, kD, 0, 0, qkvT, kD, 0, 0, QKg, kNQK, 0, 0, kD, cbias,
          (float*)VTg, 0);

      float* lr0 = lbuf + (size_t)g * 8 * kS;
      // QK^T for all nb*8 (b,h): A = Q cols, B = K cols of QKg (BM=256)
      k_qkt<<<dim3(kS / 256, 16, zc8), 256, 0, stream>>>(
          QKg, kNQK, kD, sHiA, QKg + kND, kNQK, kD, sHiA, Sb, kS, sS, 0, kD,
          nullptr, lr0, kS);
      // P@V (BM=256, BN=128): A = S, B = VTg, C = AOg (aliases QKg)
      k_pv128<<<dim3(kS / 256, 4, zc8), 256, 0, stream>>>(
          Sb, kS, sS, 0, VTg, kS, (i64)kD * kS, 0, AOg, kND, kD, sHiAO, kS,
          nullptr, lr0, kS);
      // O-projection, split-K=4 via z (K=1024 each), partials -> Pb
      k_osplit<<<dim3(nb * kS / 128, kD / 64, 4), 256, 0, stream>>>(
          AOg, kND, 1024, 0, owT, kND, 1024, 0, Pb, kD, (i64)nb * kS * kD, 0,
          1024, nullptr, nullptr, 0);
      k_red4<<<dim3(nb * kS * kD / 4 / 256), 256, 0, stream>>>(
          Pb, o_b, out + (size_t)g * kS * kD, nb * kS * kD / 4);
    }
  } else if (plan == 1 || plan == 2) {
    u16* Qh = (u16*)alloc(SZ_H);
    u16* Kh = (u16*)alloc(SZ_H);
    u16* Vh = (u16*)alloc(SZ_H);
    u16* VTh = (u16*)alloc(SZ_H);
    u16* AO = (u16*)alloc(plan == 1 ? SZ_AO : SZ_H);
    u16* Sb = (u16*)alloc((size_t)zc * SZ_S);
    const int aold = (plan == 1) ? kND : kD;

    for (int h = 0; h < kH; h++) {
      const u16* qwh = qkvT + (size_t)h * kD * kD;
      const u16* kwh = kwT + (size_t)h * kD * kD;
      const u16* vwh = vwT + (size_t)h * kD * kD;
      k_qkproj<<<dim3(64, 4), 256, 0, stream>>>(xn, kD, 0, 0, qwh, kD, 0, 0,
                                                Qh, kD, 0, 0, kD, q_b + h * kD,
                                                nullptr, 0);
      k_qkproj<<<dim3(64, 4), 256, 0, stream>>>(xn, kD, 0, 0, kwh, kD, 0, 0,
                                                Kh, kD, 0, 0, kD, k_b + h * kD,
                                                nullptr, 0);
      k_qkproj<<<dim3(64, 4), 256, 0, stream>>>(xn, kD, 0, 0, vwh, kD, 0, 0,
                                                Vh, kD, 0, 0, kD, v_b + h * kD,
                                                nullptr, 0);
      k_vt<<<dim3(64, 16, 4), tb, 0, stream>>>(Vh, VTh, kD, (i64)kS * kD, 0,
                                               (i64)kD * kS);
      u16* AOh = (plan == 1) ? AO + (size_t)h * kD : AO;
      const i64 sAO = (plan == 1) ? (i64)kS * kND : (i64)kS * kD;
      for (int b0 = 0; b0 < kB; b0 += zc) {
        float* lr0 = lbuf + (size_t)(h * 4 + b0) * kS;
        k_qkt<<<dim3(kS / 256, 16, zc), 256, 0, stream>>>(
            Qh + (size_t)b0 * kS * kD, kD, (i64)kS * kD, 0,
            Kh + (size_t)b0 * kS * kD, kD, (i64)kS * kD, 0, Sb, kS, sS, 0, kD,
            nullptr, lr0, kS);
        k_pv<<<dim3(16, 8, zc), 256, 0, stream>>>(
            Sb, kS, sS, 0, VTh + (size_t)b0 * kD * kS, kS, (i64)kD * kS, 0,
            AOh + (size_t)b0 * kS * aold, aold, sAO, 0, kS, nullptr, lr0, kS);
      }
      if (plan == 2) {
        if (h == 0)
          k_oproj<<<dim3(64, 4), 256, 0, stream>>>(
              AO, kD, 0, 0, owT + (size_t)h * kD, kND, 0, 0, out, kD, 0, 0, kD,
              o_b, nullptr, 0);
        else
          k_oacc<<<dim3(64, 4), 256, 0, stream>>>(
              AO, kD, 0, 0, owT + (size_t)h * kD, kND, 0, 0, out, kD, 0, 0, kD,
              nullptr, nullptr, 0);
      }
    }
    if (plan == 1)
      k_oproj<<<dim3(64, 4), 256, 0, stream>>>(AO, kND, 0, 0, owT, kND, 0, 0,
                                               out, kD, 0, 0, kND, o_b,
                                               nullptr, 0);
  } else {
    u16* Qbh = (u16*)alloc(SZ_BH);
    u16* Kbh = (u16*)alloc(SZ_BH);
    u16* Vbh = (u16*)alloc(SZ_BH);
    u16* VTbh = (u16*)alloc(SZ_BH);
    u16* AObh = (u16*)alloc(SZ_BH);
    u16* Sb = (u16*)alloc(SZ_S);

    for (int b = 0; b < kB; b++)
      for (int h = 0; h < kH; h++) {
        const u16* xb = xn + (size_t)b * kS * kD;
        k_qkproj<<<dim3(16, 4), 256, 0, stream>>>(
            xb, kD, 0, 0, qkvT + (size_t)h * kD * kD, kD, 0, 0, Qbh, kD, 0, 0,
            kD, q_b + h * kD, nullptr, 0);
        k_qkproj<<<dim3(16, 4), 256, 0, stream>>>(
            xb, kD, 0, 0, kwT + (size_t)h * kD * kD, kD, 0, 0, Kbh, kD, 0, 0,
            kD, k_b + h * kD, nullptr, 0);
        k_qkproj<<<dim3(16, 4), 256, 0, stream>>>(
            xb, kD, 0, 0, vwT + (size_t)h * kD * kD, kD, 0, 0, Vbh, kD, 0, 0,
            kD, v_b + h * kD, nullptr, 0);
        k_vt<<<dim3(64, 16, 1), tb, 0, stream>>>(Vbh, VTbh, kD, 0, 0, 0);
        float* lr0 = lbuf + (size_t)(b * 8 + h) * kS;
        k_qkt<<<dim3(kS / 256, 16, 1), 256, 0, stream>>>(
            Qbh, kD, 0, 0, Kbh, kD, 0, 0, Sb, kS, 0, 0, kD, nullptr, lr0, 0);
        k_pv<<<dim3(16, 8, 1), 256, 0, stream>>>(
            Sb, kS, 0, 0, VTbh, kS, 0, 0, AObh, kD, 0, 0, kS, nullptr, lr0, 0);
        float* outb = out + (size_t)b * kS * kD;
        if (h == 0)
          k_oproj<<<dim3(16, 4), 256, 0, stream>>>(
              AObh, kD, 0, 0, owT, kND, 0, 0, outb, kD, 0, 0, kD, o_b, nullptr,
              0);
        else
          k_oacc<<<dim3(16, 4), 256, 0, stream>>>(
              AObh, kD, 0, 0, owT + (size_t)h * kD, kND, 0, 0, outb, kD, 0, 0,
              kD, nullptr, nullptr, 0);
      }
  }
}

// Round 18
// 627.775 us; speedup vs baseline: 1.0862x; 1.0862x over previous
//
#include <hip/hip_runtime.h>

typedef unsigned short u16;
typedef unsigned int u32;
typedef long long i64;
typedef __attribute__((ext_vector_type(4))) float f32x4;
typedef __attribute__((ext_vector_type(8))) __bf16 bf16x8;

#define DEVI static __device__ __forceinline__

constexpr int kB = 4, kS = 2048, kD = 512, kH = 8;
constexpr int kND = kD * kH;     // 4096
constexpr int kBS = kB * kS;     // 8192
constexpr int kNQK = 2 * kND;    // 8192
constexpr int kNQKV = 3 * kND;   // 12288
constexpr float kScale = 0.044194173824159216f;  // 512^-0.5

DEVI u16 f2bf(float f) {
  u32 u = __builtin_bit_cast(u32, f);
  return (u16)((u + 0x7fffu + ((u >> 16) & 1u)) >> 16);
}
DEVI float bf2f(u16 h) { return __builtin_bit_cast(float, (u32)h << 16); }

DEVI f32x4 mfma16(bf16x8 a, bf16x8 b, f32x4 c) {
  return __builtin_amdgcn_mfma_f32_16x16x32_bf16(a, b, c, 0, 0, 0);
}

// global -> LDS direct DMA, 16B per lane (wave-uniform LDS base + lane*16)
DEVI void gld16(const u16* g, u16* l) {
  __builtin_amdgcn_global_load_lds(
      (const __attribute__((address_space(1))) void*)g,
      (__attribute__((address_space(3))) void*)l, 16, 0, 0);
}

__global__ void k_zero(float* __restrict__ p, int n) {
  int i = blockIdx.x * 256 + threadIdx.x;
  if (i < n) p[i] = 0.0f;
}

// concat q_b|k_b|v_b -> [12288]
__global__ void k_cat3(const float* __restrict__ a, const float* __restrict__ b,
                       const float* __restrict__ c, float* __restrict__ o) {
  int i = blockIdx.x * 256 + threadIdx.x;
  if (i < kND) o[i] = a[i];
  else if (i < 2 * kND) o[i] = b[i - kND];
  else if (i < 3 * kND) o[i] = c[i - 2 * kND];
}

// sum 4 split-K partial planes + bias -> fp32 out; NP = float4s per plane
__global__ __launch_bounds__(256) void k_red4(const float* __restrict__ p,
                                              const float* __restrict__ bias,
                                              float* __restrict__ out, int NP) {
  const int i = blockIdx.x * 256 + threadIdx.x;  // float4 index
  const float4* pv = reinterpret_cast<const float4*>(p);
  const float4 a = pv[i], b = pv[i + NP], c = pv[i + 2 * NP],
               d = pv[i + 3 * NP];
  const float4 bv = reinterpret_cast<const float4*>(bias)[i & 127];
  float4 r;
  r.x = a.x + b.x + c.x + d.x + bv.x;
  r.y = a.y + b.y + c.y + d.y + bv.y;
  r.z = a.z + b.z + c.z + d.z + bv.z;
  r.w = a.w + b.w + c.w + d.w + bv.w;
  reinterpret_cast<float4*>(out)[i] = r;
}

// ---------------- LayerNorm: fp32 [8192,512] -> bf16 xn ----------------
__global__ __launch_bounds__(256) void k_ln(const float* __restrict__ x,
                                            const float* __restrict__ lw,
                                            const float* __restrict__ lb,
                                            u16* __restrict__ xn) {
  const int lane = threadIdx.x & 63;
  const int row = (blockIdx.x << 2) + (threadIdx.x >> 6);
  const float4* xp = reinterpret_cast<const float4*>(x + (size_t)row * kD);
  float4 a = xp[lane * 2], b = xp[lane * 2 + 1];
  float s = a.x + a.y + a.z + a.w + b.x + b.y + b.z + b.w;
  float ss = a.x * a.x + a.y * a.y + a.z * a.z + a.w * a.w +
             b.x * b.x + b.y * b.y + b.z * b.z + b.w * b.w;
#pragma unroll
  for (int m = 1; m < 64; m <<= 1) {
    s += __shfl_xor(s, m, 64);
    ss += __shfl_xor(ss, m, 64);
  }
  const float mean = s * (1.0f / kD);
  const float var = ss * (1.0f / kD) - mean * mean;
  const float rstd = rsqrtf(fmaxf(var, 0.0f) + 1e-5f);
  const float4* wp = reinterpret_cast<const float4*>(lw);
  const float4* bp = reinterpret_cast<const float4*>(lb);
  float4 w0 = wp[lane * 2], w1 = wp[lane * 2 + 1];
  float4 b0 = bp[lane * 2], b1 = bp[lane * 2 + 1];
  float o0 = (a.x - mean) * rstd * w0.x + b0.x;
  float o1 = (a.y - mean) * rstd * w0.y + b0.y;
  float o2 = (a.z - mean) * rstd * w0.z + b0.z;
  float o3 = (a.w - mean) * rstd * w0.w + b0.w;
  float o4 = (b.x - mean) * rstd * w1.x + b1.x;
  float o5 = (b.y - mean) * rstd * w1.y + b1.y;
  float o6 = (b.z - mean) * rstd * w1.z + b1.z;
  float o7 = (b.w - mean) * rstd * w1.w + b1.w;
  uint4 st = make_uint4((u32)f2bf(o0) | ((u32)f2bf(o1) << 16),
                        (u32)f2bf(o2) | ((u32)f2bf(o3) << 16),
                        (u32)f2bf(o4) | ((u32)f2bf(o5) << 16),
                        (u32)f2bf(o6) | ((u32)f2bf(o7) << 16));
  *reinterpret_cast<uint4*>(xn + (size_t)row * kD + lane * 8) = st;
}

// ------------- weight transpose: fp32 [R,C] -> bf16 [C,R] -------------
__global__ void k_wt(const float* __restrict__ in, u16* __restrict__ out,
                     int R, int C) {
  __shared__ float t[32][33];
  const int tx = threadIdx.x, ty = threadIdx.y;
  const int c0 = blockIdx.x << 5, r0 = blockIdx.y << 5;
#pragma unroll
  for (int i = 0; i < 4; i++)
    t[ty + 8 * i][tx] = in[(size_t)(r0 + ty + 8 * i) * C + c0 + tx];
  __syncthreads();
#pragma unroll
  for (int i = 0; i < 4; i++)
    out[(size_t)(c0 + ty + 8 * i) * R + r0 + tx] = f2bf(t[tx][ty + 8 * i]);
}

// fused transpose of q_w/k_w/v_w (each fp32 [512,4096] -> bf16 [4096,512])
// into contiguous qkvT slices; z selects the weight.
__global__ void k_wt3(const float* __restrict__ qa, const float* __restrict__ kb,
                      const float* __restrict__ vc, u16* __restrict__ out) {
  __shared__ float t[32][33];
  const int z = blockIdx.z;
  const float* in = (z == 0) ? qa : (z == 1) ? kb : vc;
  u16* o = out + (size_t)z * kND * kD;
  const int tx = threadIdx.x, ty = threadIdx.y;
  const int c0 = blockIdx.x << 5, r0 = blockIdx.y << 5;
#pragma unroll
  for (int i = 0; i < 4; i++)
    t[ty + 8 * i][tx] = in[(size_t)(r0 + ty + 8 * i) * kND + c0 + tx];
  __syncthreads();
#pragma unroll
  for (int i = 0; i < 4; i++)
    o[(size_t)(c0 + ty + 8 * i) * kD + r0 + tx] = f2bf(t[tx][ty + 8 * i]);
}

// ------- V transpose: bf16 V[2048, d-slice] -> VT[z][512][2048] -------
// (used only by fallback plans)
__global__ void k_vt(const u16* __restrict__ V, u16* __restrict__ VT, int ldv,
                     i64 sVz, i64 sVzH, i64 sTz) {
  const int z = blockIdx.z;
  V += (size_t)((i64)z * sVz + (i64)(z >> 3) * sVzH);
  VT += (size_t)((i64)z * sTz);
  __shared__ u16 t[32][33];
  const int tx = threadIdx.x, ty = threadIdx.y;
  const int s0 = blockIdx.x << 5, d0 = blockIdx.y << 5;
#pragma unroll
  for (int i = 0; i < 4; i++)
    t[ty + 8 * i][tx] = V[(size_t)(s0 + ty + 8 * i) * ldv + d0 + tx];
  __syncthreads();
#pragma unroll
  for (int i = 0; i < 4; i++)
    VT[(size_t)(d0 + ty + 8 * i) * kS + s0 + tx] = t[tx][ty + 8 * i];
}

// LDS-transposed C-store index (128-row staging tiles): elem (row,col) at
// row*128 + ((col>>3) ^ (((row>>2)&3)<<1))*8 + (col&7).
DEVI int tidx(int row, int col) {
  return row * 128 + ((((col >> 3) ^ (((row >> 2) & 3) << 1)) << 3) |
                      (col & 7));
}

// ---------------- GEMM body: C[M,N] = A[M,K] * Bt[N,K]^T (+epilogue) -------
// FINAL measured-best configuration (R16, 629 us; session 1086 -> 629):
//  - qkt: BM=128 + DEPTH=3. Both neighbors measured worse: BM=256 +20%
//    (R11/R17 -- short K never fills the pipeline, regs halve occupancy);
//    DEPTH=2 +4% (R12).
//  - pv128: BM=256 + DEPTH=3 (BM=128/BN=64 slower, R7/R10).
//  - proj/osplit: DEPTH=2 (DEPTH=3 cuts occupancy 5->3 blk/CU, R13).
//  - osplit: f32 partial planes + k_red4 (atomic accumulate +29 us, R15).
// T1: XCD-chunked bijective block remap (m204). Source+read chunk swizzle.
// EPI 0: bf16 out + bias (LDS-staged coalesced store)        (proj)
// EPI 1: f32  out + bias                                     (O-proj fallback)
// EPI 4: f32  out += acc                                     (O-proj accum)
// EPI 2: bf16 out = exp(acc*scale), atomic row-sums -> lrow  (QK^T)
// EPI 3: bf16 out = acc / lrow[row]                          (P@V)
// EPI 6: f32 partial out (split-K plane per z)               (O-proj)
// EPI 7: fused QKV proj: n0 < 8192 -> EPI0 into Cb; else V into lbase (VT)
template <int EPI, int BN, int BM = 128, int DEPTH = 2>
DEVI void gemm_body(const u16* __restrict__ A, int lda, i64 sAz, i64 sAzH,
                    const u16* __restrict__ Bt, int ldb, i64 sBz, i64 sBzH,
                    void* __restrict__ Cb, int ldc, i64 sCz, i64 sCzH, int K,
                    const float* __restrict__ bias, float* __restrict__ lbase,
                    i64 sLz) {
  constexpr int NF = BN / 32;    // B-frags per wave
  constexpr int MF = BM / 32;    // A-frags per wave
  constexpr int BHALF = BN / 2;  // cols per wave-col
  constexpr int WM = BM / 2;     // rows per wave-row
  constexpr int ABUF = BM * 32, BBUF = BN * 32;  // elems per LDS buffer
  constexpr int NCA = BM / 64, NCB = BN / 64;    // gld16 chunks per wave
  constexpr int NLD = NCA + NCB;                 // per-wave loads per stage
  constexpr int H = BM / 128;    // epilogue flush halves

  // ---- T1 bijective XCD remap (correctness-neutral relabeling) ----
  const u32 gxd = gridDim.x, gyd = gridDim.y;
  const u32 total = gxd * gyd * gridDim.z;
  u32 fid = (blockIdx.z * gyd + blockIdx.y) * gxd + blockIdx.x;
  {
    const u32 q = total >> 3, r = total & 7;
    const u32 xcd = fid & 7, i = fid >> 3;
    fid = (xcd < r ? xcd * (q + 1) : r * (q + 1) + (xcd - r) * q) + i;
  }
  const int bx = fid % gxd;
  const int by = (fid / gxd) % gyd;
  const int z = fid / (gxd * gyd);

  A += (size_t)((i64)z * sAz + (i64)(z >> 3) * sAzH);
  Bt += (size_t)((i64)z * sBz + (i64)(z >> 3) * sBzH);
  const i64 czoff = (i64)z * sCz + (i64)(z >> 3) * sCzH;
  float* lrow = lbase + (size_t)z * sLz;

  __shared__ __align__(16) u16 smem[DEPTH * (ABUF + BBUF)];
  u16* Asb = smem;
  u16* Bsb = smem + DEPTH * ABUF;

  const int tid = threadIdx.x;
  const int lane = tid & 63, wid = tid >> 6;
  const int g = lane >> 4, lr = lane & 15;
  const int wr = wid >> 1, wc = wid & 1;
  const int m0 = bx * BM, n0 = by * BN;

  // staging: wave w covers A rows [w*BM/4, +BM/4) in NCA 16-row chunks;
  // B rows likewise. Chunk-XOR swizzle on the global source (row&3 ==
  // (lane>>2)&3 for all staged rows since chunk offsets are multiples of 16).
  const int scol = (((lane & 3) ^ ((lane >> 2) & 3)) << 3);
  const int l4 = lane >> 2;
  const u16* agp[NCA];
#pragma unroll
  for (int c = 0; c < NCA; c++)
    agp[c] = A + (size_t)(m0 + wid * (BM / 4) + 16 * c + l4) * lda + scol;
  const u16* bgp[NCB];
#pragma unroll
  for (int c = 0; c < NCB; c++)
    bgp[c] = Bt + (size_t)(n0 + wid * (BN / 4) + 16 * c + l4) * ldb + scol;

  f32x4 acc[MF][NF] = {};

  auto stage = [&](int ks, int buf) {
    const int ko = ks << 5;
    u16* ab = Asb + buf * ABUF + wid * (BM / 4) * 32;
#pragma unroll
    for (int c = 0; c < NCA; c++) gld16(agp[c] + ko, ab + c * 512);
    u16* bb = Bsb + buf * BBUF + wid * (BN / 4) * 32;
#pragma unroll
    for (int c = 0; c < NCB; c++) gld16(bgp[c] + ko, bb + c * 512);
  };

  // read-side swizzle: fragment rows R have R&3 == lr&3
  const int gx8 = ((g ^ (lr & 3)) << 3);

  const int nsteps = K >> 5;
  if constexpr (DEPTH == 2) {
    stage(0, 0);
    for (int ks = 0; ks < nsteps; ++ks) {
      const int cur = ks & 1;
      __syncthreads();  // drains vmcnt -> tile `cur` ready; prior reads done
      if (ks + 1 < nsteps) stage(ks + 1, cur ^ 1);
      bf16x8 af[MF], bfr[NF];
#pragma unroll
      for (int m = 0; m < MF; m++)
        af[m] = *reinterpret_cast<const bf16x8*>(
            &Asb[cur * ABUF + (wr * WM + m * 16 + lr) * 32 + gx8]);
#pragma unroll
      for (int n = 0; n < NF; n++)
        bfr[n] = *reinterpret_cast<const bf16x8*>(
            &Bsb[cur * BBUF + (wc * BHALF + n * 16 + lr) * 32 + gx8]);
#pragma unroll
      for (int m = 0; m < MF; m++)
#pragma unroll
        for (int n = 0; n < NF; n++)
          acc[m][n] = mfma16(af[m], bfr[n], acc[m][n]);
    }
  } else {
    stage(0, 0);
    stage(1, 1);
    for (int ks = 0; ks < nsteps; ++ks) {
      const int cur = ks % 3;
      // tile ks must be landed; newest stage (tile ks+1) may stay in flight
      if (ks + 1 < nsteps) {
        if constexpr (NLD == 3) asm volatile("s_waitcnt vmcnt(3)" ::: "memory");
        else if constexpr (NLD == 4) asm volatile("s_waitcnt vmcnt(4)" ::: "memory");
        else if constexpr (NLD == 6) asm volatile("s_waitcnt vmcnt(6)" ::: "memory");
        else asm volatile("s_waitcnt vmcnt(0)" ::: "memory");
      } else {
        asm volatile("s_waitcnt vmcnt(0)" ::: "memory");
      }
      __builtin_amdgcn_s_barrier();
      if (ks + 2 < nsteps) stage(ks + 2, (ks + 2) % 3);
      bf16x8 af[MF], bfr[NF];
#pragma unroll
      for (int m = 0; m < MF; m++)
        af[m] = *reinterpret_cast<const bf16x8*>(
            &Asb[cur * ABUF + (wr * WM + m * 16 + lr) * 32 + gx8]);
#pragma unroll
      for (int n = 0; n < NF; n++)
        bfr[n] = *reinterpret_cast<const bf16x8*>(
            &Bsb[cur * BBUF + (wc * BHALF + n * 16 + lr) * 32 + gx8]);
      asm volatile("s_waitcnt lgkmcnt(0)" ::: "memory");
      __builtin_amdgcn_sched_barrier(0);
      __builtin_amdgcn_s_setprio(1);
#pragma unroll
      for (int m = 0; m < MF; m++)
#pragma unroll
        for (int n = 0; n < NF; n++)
          acc[m][n] = mfma16(af[m], bfr[n], acc[m][n]);
      __builtin_amdgcn_s_setprio(0);
    }
  }

  const int crow0 = m0 + wr * WM;
  const int ccol0 = n0 + wc * BHALF;

  // coalesced bf16 readout of 128-row staging tile -> global (BN=128 only)
  auto flushRows = [&](u16* C16, int ld, int rbase) {
#pragma unroll
    for (int it = 0; it < 8; ++it) {
      const int r = it * 16 + (tid >> 4);
      const int b = tid & 15;
      const int sb = b ^ (((r >> 2) & 3) << 1);
      *reinterpret_cast<uint4*>(C16 + (size_t)(m0 + rbase + r) * ld + n0 +
                                b * 8) =
          *reinterpret_cast<const uint4*>(&smem[r * 128 + sb * 8]);
    }
  };

  if constexpr (EPI == 0 || EPI == 7) {
    const bool qkpart = (EPI == 0) || (n0 < kNQK);
    if (qkpart) {
      __syncthreads();  // K-loop LDS dead; reuse as staging tile
#pragma unroll
      for (int n = 0; n < NF; n++) {
        const int cl = wc * BHALF + n * 16 + lr;
        const float bv = bias[n0 + cl];
#pragma unroll
        for (int m = 0; m < MF; m++)
#pragma unroll
          for (int j = 0; j < 4; j++) {
            const int rl = wr * WM + m * 16 + (g << 2) + j;
            smem[tidx(rl, cl)] = f2bf(acc[m][n][j] + bv);
          }
      }
      u16* C16 = (u16*)Cb + (size_t)czoff;
      __syncthreads();
      flushRows(C16, ldc, 0);
    } else {
      // V branch of fused proj: transposed write into VT[zb][d][s]
      u16* T = smem;
      __syncthreads();
      const int ndl = n0 - kNQK;  // d-col base within [0,4096)
#pragma unroll
      for (int n = 0; n < NF; n++) {
        const int cl = wc * BHALF + n * 16 + lr;  // d_local
        const float bv = bias[n0 + cl];
#pragma unroll
        for (int m = 0; m < MF; m++) {
          const int rlb = wr * WM + m * 16 + (g << 2);  // s_local base
#pragma unroll
          for (int j = 0; j < 4; j++) {
            const int rl = rlb + j;
            T[cl * 128 + ((((rl >> 3) ^ (cl & 7)) << 3) | (rl & 7))] =
                f2bf(acc[m][n][j] + bv);
          }
        }
      }
      __syncthreads();
      const int zb = ((m0 >> 11) << 3) + (ndl >> 9);  // b'*8 + h
      u16* VT = (u16*)lbase + (size_t)zb * kD * kS +
                (size_t)(ndl & 511) * kS + (m0 & 2047);
#pragma unroll
      for (int p = 0; p < 8; p++) {
        const int dl = p * 16 + (tid >> 4);
        const int r8 = tid & 15;
        *reinterpret_cast<uint4*>(VT + (size_t)dl * kS + (r8 << 3)) =
            *reinterpret_cast<const uint4*>(
                &T[dl * 128 + ((r8 ^ (dl & 7)) << 3)]);
      }
    }
  } else if constexpr (EPI == 1 || EPI == 4 || EPI == 6) {
    float* C32 = (float*)Cb + (size_t)czoff;
#pragma unroll
    for (int n = 0; n < NF; n++) {
      const int col = ccol0 + n * 16 + lr;
      const float bv = (EPI == 1) ? bias[col] : 0.0f;
#pragma unroll
      for (int m = 0; m < MF; m++)
#pragma unroll
        for (int j = 0; j < 4; j++) {
          const int row = crow0 + m * 16 + (g << 2) + j;
          float v = acc[m][n][j] + bv;
          if constexpr (EPI == 4) v += C32[(size_t)row * ldc + col];
          C32[(size_t)row * ldc + col] = v;
        }
    }
  } else if constexpr (EPI == 2) {
    u16* C16 = (u16*)Cb + (size_t)czoff;
#pragma unroll
    for (int h = 0; h < H; ++h) {
      __syncthreads();  // K-loop reads / previous flush done
      if (H == 1 || wr == h) {
#pragma unroll
        for (int m = 0; m < MF; m++) {
          float rsum[4] = {0.f, 0.f, 0.f, 0.f};
#pragma unroll
          for (int n = 0; n < NF; n++) {
            const int cl = wc * BHALF + n * 16 + lr;
#pragma unroll
            for (int j = 0; j < 4; j++) {
              const int rl = wr * WM - h * 128 + m * 16 + (g << 2) + j;
              const float p = __expf(acc[m][n][j] * kScale);
              const u16 pb = f2bf(p);
              smem[tidx(rl, cl)] = pb;
              rsum[j] += bf2f(pb);  // keep l consistent with stored bf16 P
            }
          }
#pragma unroll
          for (int j = 0; j < 4; j++) {
            float r = rsum[j];
            r += __shfl_xor(r, 1, 64);
            r += __shfl_xor(r, 2, 64);
            r += __shfl_xor(r, 4, 64);
            r += __shfl_xor(r, 8, 64);
            if (lr == 0) atomicAdd(&lrow[crow0 + m * 16 + (g << 2) + j], r);
          }
        }
      }
      __syncthreads();
      flushRows(C16, ldc, h * 128);
    }
  } else if constexpr (EPI == 3) {
    if constexpr (BN == 128) {
      u16* C16 = (u16*)Cb + (size_t)czoff;
#pragma unroll
      for (int h = 0; h < H; ++h) {
        __syncthreads();
        if (H == 1 || wr == h) {
#pragma unroll
          for (int m = 0; m < MF; m++)
#pragma unroll
            for (int j = 0; j < 4; j++) {
              const int rl = wr * WM - h * 128 + m * 16 + (g << 2) + j;
              const float inv = 1.0f / lrow[crow0 + m * 16 + (g << 2) + j];
#pragma unroll
              for (int n = 0; n < NF; n++) {
                const int cl = wc * BHALF + n * 16 + lr;
                smem[tidx(rl, cl)] = f2bf(acc[m][n][j] * inv);
              }
            }
        }
        __syncthreads();
        flushRows(C16, ldc, h * 128);
      }
    } else {
      u16* C16 = (u16*)Cb + (size_t)czoff;
#pragma unroll
      for (int m = 0; m < MF; m++)
#pragma unroll
        for (int j = 0; j < 4; j++) {
          const int row = crow0 + m * 16 + (g << 2) + j;
          const float inv = 1.0f / lrow[row];
#pragma unroll
          for (int n = 0; n < NF; n++) {
            const int col = ccol0 + n * 16 + lr;
            C16[(size_t)row * ldc + col] = f2bf(acc[m][n][j] * inv);
          }
        }
    }
  }
}

#define GEMM_ARGS                                                             \
  const u16 *A, int lda, i64 sAz, i64 sAzH, const u16 *Bt, int ldb, i64 sBz,  \
      i64 sBzH, void *Cb, int ldc, i64 sCz, i64 sCzH, int K,                  \
      const float *bias, float *lbase, i64 sLz
#define GEMM_PASS A, lda, sAz, sAzH, Bt, ldb, sBz, sBzH, Cb, ldc, sCz, sCzH, \
      K, bias, lbase, sLz

__global__ __launch_bounds__(256) void k_qkproj(GEMM_ARGS) {
  gemm_body<0, 128, 128, 2>(GEMM_PASS);
}
__global__ __launch_bounds__(256) void k_qkvproj(GEMM_ARGS) {
  gemm_body<7, 128, 128, 2>(GEMM_PASS);
}
// QK^T: BM=128 + DEPTH=3 counted-vmcnt (measured best; BM=256 regressed 2x)
__global__ __launch_bounds__(256) void k_qkt(GEMM_ARGS) {
  gemm_body<2, 128, 128, 3>(GEMM_PASS);
}
__global__ __launch_bounds__(256) void k_pv(GEMM_ARGS) {
  gemm_body<3, 64, 128, 2>(GEMM_PASS);
}
// PV: BM=256 (2 blk/CU reg-capped) + DEPTH=3 pipeline
__global__ __launch_bounds__(256, 2) void k_pv128(GEMM_ARGS) {
  gemm_body<3, 128, 256, 3>(GEMM_PASS);
}
// O-proj split-K: f32 partial planes (measured best; atomics regressed)
__global__ __launch_bounds__(256) void k_osplit(GEMM_ARGS) {
  gemm_body<6, 64, 128, 2>(GEMM_PASS);
}
__global__ __launch_bounds__(256) void k_oproj(GEMM_ARGS) {
  gemm_body<1, 128, 128, 2>(GEMM_PASS);
}
__global__ __launch_bounds__(256) void k_oacc(GEMM_ARGS) {
  gemm_body<4, 128, 128, 2>(GEMM_PASS);
}

extern "C" void kernel_launch(void* const* d_in, const int* in_sizes, int n_in,
                              void* d_out, int out_size, void* d_ws,
                              size_t ws_size, hipStream_t stream) {
  const float* x = (const float*)d_in[0];
  const float* ln_w = (const float*)d_in[1];
  const float* ln_b = (const float*)d_in[2];
  const float* q_w = (const float*)d_in[3];
  const float* q_b = (const float*)d_in[4];
  const float* k_w = (const float*)d_in[5];
  const float* k_b = (const float*)d_in[6];
  const float* v_w = (const float*)d_in[7];
  const float* v_b = (const float*)d_in[8];
  const float* o_w = (const float*)d_in[9];
  const float* o_b = (const float*)d_in[10];
  float* out = (float*)d_out;

  // ---- workspace plan, adaptive to ws_size ----
  constexpr size_t SZ_XN = (size_t)kBS * kD * 2;        // 8 MB
  constexpr size_t SZ_QKVT = (size_t)kNQKV * kD * 2;    // 12 MB
  constexpr size_t SZ_OWT = (size_t)kND * kD * 2;       // 4 MB
  constexpr size_t SZ_CB = (size_t)kNQKV * 4;           // 48 KB
  constexpr size_t SZ_LB = (size_t)32 * kS * 4;         // 256 KB
  // per-batch fused-tier pieces:
  constexpr size_t SZ_QK1 = (size_t)kS * kNQK * 2;      // 32 MB (AO aliases)
  constexpr size_t SZ_VT1 = (size_t)8 * kD * kS * 2;    // 16 MB
  constexpr size_t SZ_S1 = (size_t)8 * kS * kS * 2;     // 64 MB
  constexpr size_t SZ_TIER = SZ_QK1 + SZ_VT1 + SZ_S1;   // 112 MB per batch
  // fallback pieces:
  constexpr size_t SZ_AO = (size_t)kBS * kND * 2;       // 64 MB
  constexpr size_t SZ_S = (size_t)kS * kS * 2;          // 8 MB per z
  constexpr size_t SZ_H = (size_t)kBS * kD * 2;         // 8 MB per head
  constexpr size_t SZ_BH = (size_t)kS * kD * 2;         // 2 MB per (b,h)
  const size_t common = SZ_XN + SZ_QKVT + SZ_OWT + SZ_CB + SZ_LB;

  char* p = (char*)d_ws;
  auto alloc = [&](size_t bytes) {
    char* r = p;
    p += (bytes + 255) & ~(size_t)255;
    return r;
  };
  auto fits = [&](size_t extra) { return common + extra + 8192 <= ws_size; };

  int nb = 0, plan = -1, zc = 0;
  if (fits(4 * SZ_TIER)) nb = 4;
  else if (fits(2 * SZ_TIER)) nb = 2;
  else if (fits(1 * SZ_TIER)) nb = 1;
  else if (fits(4 * SZ_H + SZ_AO + 4 * SZ_S)) { plan = 1; zc = 4; }
  else if (fits(4 * SZ_H + SZ_AO + 1 * SZ_S)) { plan = 1; zc = 1; }
  else if (fits(5 * SZ_H + 4 * SZ_S)) { plan = 2; zc = 4; }
  else if (fits(5 * SZ_H + 1 * SZ_S)) { plan = 2; zc = 1; }
  else { plan = 3; zc = 1; }

  u16* xn = (u16*)alloc(SZ_XN);
  u16* qkvT = (u16*)alloc(SZ_QKVT);  // q rows [0,4096), k [4096,8192), v [8192,12288)
  u16* owT = (u16*)alloc(SZ_OWT);
  float* cbias = (float*)alloc(SZ_CB);
  float* lbuf = (float*)alloc(SZ_LB);

  u16* kwT = qkvT + (size_t)kND * kD;
  u16* vwT = qkvT + (size_t)2 * kND * kD;

  // ---- common pre-work ----
  k_zero<<<dim3(256), 256, 0, stream>>>(lbuf, 32 * kS);
  k_ln<<<dim3(kBS / 4), 256, 0, stream>>>(x, ln_w, ln_b, xn);
  dim3 tb(32, 8);
  k_wt3<<<dim3(kND / 32, kD / 32, 3), tb, 0, stream>>>(q_w, k_w, v_w, qkvT);
  k_wt<<<dim3(kD / 32, kND / 32), tb, 0, stream>>>(o_w, owT, kND, kD);

  const i64 sS = (i64)kS * kS;  // S tile stride (elems)

  if (nb > 0) {
    // ---- fused batch-group plan ----
    u16* QKg = (u16*)alloc((size_t)nb * SZ_QK1);
    u16* VTg = (u16*)alloc((size_t)nb * SZ_VT1);
    u16* Sb = (u16*)alloc((size_t)nb * SZ_S1);
    u16* AOg = QKg;           // [nb*2048, 4096] alias; QK dead after qkt
    float* Pb = (float*)Sb;   // split-K partials alias S (dead after pv)

    k_cat3<<<dim3(kNQKV / 256), 256, 0, stream>>>(q_b, k_b, v_b, cbias);

    const i64 sHiA = (i64)kS * kNQK - 8 * kD;   // QK z-jump at batch boundary
    const i64 sHiAO = (i64)kS * kND - 8 * kD;   // AO z-jump at batch boundary
    const int zc8 = nb * 8;

    for (int g = 0; g < kB; g += nb) {
      const u16* xb = xn + (size_t)g * kS * kD;
      // fused QKV projection: [nb*2048,512] x [12288,512]^T
      // cols <8192 -> QKg (bf16+bias); cols >=8192 -> VTg transposed
      k_qkvproj<<<dim3(nb * kS / 128, kNQKV / 128), 256, 0, stream>>>(
          xb, kD, 0, 0, qkvT, kD, 0, 0, QKg, kNQK, 0, 0, kD, cbias,
          (float*)VTg, 0);

      float* lr0 = lbuf + (size_t)g * 8 * kS;
      // QK^T for all nb*8 (b,h): A = Q cols, B = K cols of QKg (BM=128)
      k_qkt<<<dim3(16, 16, zc8), 256, 0, stream>>>(
          QKg, kNQK, kD, sHiA, QKg + kND, kNQK, kD, sHiA, Sb, kS, sS, 0, kD,
          nullptr, lr0, kS);
      // P@V (BM=256, BN=128): A = S, B = VTg, C = AOg (aliases QKg)
      k_pv128<<<dim3(kS / 256, 4, zc8), 256, 0, stream>>>(
          Sb, kS, sS, 0, VTg, kS, (i64)kD * kS, 0, AOg, kND, kD, sHiAO, kS,
          nullptr, lr0, kS);
      // O-projection, split-K=4 via z (K=1024 each), partials -> Pb
      k_osplit<<<dim3(nb * kS / 128, kD / 64, 4), 256, 0, stream>>>(
          AOg, kND, 1024, 0, owT, kND, 1024, 0, Pb, kD, (i64)nb * kS * kD, 0,
          1024, nullptr, nullptr, 0);
      k_red4<<<dim3(nb * kS * kD / 4 / 256), 256, 0, stream>>>(
          Pb, o_b, out + (size_t)g * kS * kD, nb * kS * kD / 4);
    }
  } else if (plan == 1 || plan == 2) {
    u16* Qh = (u16*)alloc(SZ_H);
    u16* Kh = (u16*)alloc(SZ_H);
    u16* Vh = (u16*)alloc(SZ_H);
    u16* VTh = (u16*)alloc(SZ_H);
    u16* AO = (u16*)alloc(plan == 1 ? SZ_AO : SZ_H);
    u16* Sb = (u16*)alloc((size_t)zc * SZ_S);
    const int aold = (plan == 1) ? kND : kD;

    for (int h = 0; h < kH; h++) {
      const u16* qwh = qkvT + (size_t)h * kD * kD;
      const u16* kwh = kwT + (size_t)h * kD * kD;
      const u16* vwh = vwT + (size_t)h * kD * kD;
      k_qkproj<<<dim3(64, 4), 256, 0, stream>>>(xn, kD, 0, 0, qwh, kD, 0, 0,
                                                Qh, kD, 0, 0, kD, q_b + h * kD,
                                                nullptr, 0);
      k_qkproj<<<dim3(64, 4), 256, 0, stream>>>(xn, kD, 0, 0, kwh, kD, 0, 0,
                                                Kh, kD, 0, 0, kD, k_b + h * kD,
                                                nullptr, 0);
      k_qkproj<<<dim3(64, 4), 256, 0, stream>>>(xn, kD, 0, 0, vwh, kD, 0, 0,
                                                Vh, kD, 0, 0, kD, v_b + h * kD,
                                                nullptr, 0);
      k_vt<<<dim3(64, 16, 4), tb, 0, stream>>>(Vh, VTh, kD, (i64)kS * kD, 0,
                                               (i64)kD * kS);
      u16* AOh = (plan == 1) ? AO + (size_t)h * kD : AO;
      const i64 sAO = (plan == 1) ? (i64)kS * kND : (i64)kS * kD;
      for (int b0 = 0; b0 < kB; b0 += zc) {
        float* lr0 = lbuf + (size_t)(h * 4 + b0) * kS;
        k_qkt<<<dim3(16, 16, zc), 256, 0, stream>>>(
            Qh + (size_t)b0 * kS * kD, kD, (i64)kS * kD, 0,
            Kh + (size_t)b0 * kS * kD, kD, (i64)kS * kD, 0, Sb, kS, sS, 0, kD,
            nullptr, lr0, kS);
        k_pv<<<dim3(16, 8, zc), 256, 0, stream>>>(
            Sb, kS, sS, 0, VTh + (size_t)b0 * kD * kS, kS, (i64)kD * kS, 0,
            AOh + (size_t)b0 * kS * aold, aold, sAO, 0, kS, nullptr, lr0, kS);
      }
      if (plan == 2) {
        if (h == 0)
          k_oproj<<<dim3(64, 4), 256, 0, stream>>>(
              AO, kD, 0, 0, owT + (size_t)h * kD, kND, 0, 0, out, kD, 0, 0, kD,
              o_b, nullptr, 0);
        else
          k_oacc<<<dim3(64, 4), 256, 0, stream>>>(
              AO, kD, 0, 0, owT + (size_t)h * kD, kND, 0, 0, out, kD, 0, 0, kD,
              nullptr, nullptr, 0);
      }
    }
    if (plan == 1)
      k_oproj<<<dim3(64, 4), 256, 0, stream>>>(AO, kND, 0, 0, owT, kND, 0, 0,
                                               out, kD, 0, 0, kND, o_b,
                                               nullptr, 0);
  } else {
    u16* Qbh = (u16*)alloc(SZ_BH);
    u16* Kbh = (u16*)alloc(SZ_BH);
    u16* Vbh = (u16*)alloc(SZ_BH);
    u16* VTbh = (u16*)alloc(SZ_BH);
    u16* AObh = (u16*)alloc(SZ_BH);
    u16* Sb = (u16*)alloc(SZ_S);

    for (int b = 0; b < kB; b++)
      for (int h = 0; h < kH; h++) {
        const u16* xb = xn + (size_t)b * kS * kD;
        k_qkproj<<<dim3(16, 4), 256, 0, stream>>>(
            xb, kD, 0, 0, qkvT + (size_t)h * kD * kD, kD, 0, 0, Qbh, kD, 0, 0,
            kD, q_b + h * kD, nullptr, 0);
        k_qkproj<<<dim3(16, 4), 256, 0, stream>>>(
            xb, kD, 0, 0, kwT + (size_t)h * kD * kD, kD, 0, 0, Kbh, kD, 0, 0,
            kD, k_b + h * kD, nullptr, 0);
        k_qkproj<<<dim3(16, 4), 256, 0, stream>>>(
            xb, kD, 0, 0, vwT + (size_t)h * kD * kD, kD, 0, 0, Vbh, kD, 0, 0,
            kD, v_b + h * kD, nullptr, 0);
        k_vt<<<dim3(64, 16, 1), tb, 0, stream>>>(Vbh, VTbh, kD, 0, 0, 0);
        float* lr0 = lbuf + (size_t)(b * 8 + h) * kS;
        k_qkt<<<dim3(16, 16, 1), 256, 0, stream>>>(
            Qbh, kD, 0, 0, Kbh, kD, 0, 0, Sb, kS, 0, 0, kD, nullptr, lr0, 0);
        k_pv<<<dim3(16, 8, 1), 256, 0, stream>>>(
            Sb, kS, 0, 0, VTbh, kS, 0, 0, AObh, kD, 0, 0, kS, nullptr, lr0, 0);
        float* outb = out + (size_t)b * kS * kD;
        if (h == 0)
          k_oproj<<<dim3(16, 4), 256, 0, stream>>>(
              AObh, kD, 0, 0, owT, kND, 0, 0, outb, kD, 0, 0, kD, o_b, nullptr,
              0);
        else
          k_oacc<<<dim3(16, 4), 256, 0, stream>>>(
              AObh, kD, 0, 0, owT + (size_t)h * kD, kND, 0, 0, outb, kD, 0, 0,
              kD, nullptr, nullptr, 0);
      }
  }
}